// Round 16
// baseline (290.266 us; speedup 1.0000x reference)
//
#include <hip/hip_runtime.h>

#define BSZ 8
#define DIM 512
#define TSZ 2048
#define STEPS 12
#define NNEG 10
#define COPIES 11
#define TCH 64
#define GTCH 128

typedef unsigned short ushortT;
typedef unsigned int uintT;
typedef __attribute__((ext_vector_type(8))) short short8v;
typedef __attribute__((ext_vector_type(4))) float f32x4;

#define AS1 __attribute__((address_space(1)))
#define AS3 __attribute__((address_space(3)))

// ws layout (bytes):
//   xt : [8][2048][512] bf16 @ 0            (16,777,216)
//   yt : [8][2048][512] bf16 @ 16,777,216   (16,777,216)
//   Wco: [12][512][512] bf16 @ 33,554,432   (6,291,456)
//   xp : [8][12][2048][512] bf16 @ 39,845,888 (201,326,592)  -- Path A only
#define XP_OFF 39845888ull
#define WS_NEEDED (XP_OFF + 201326592ull)

__device__ __forceinline__ ushortT f2bf(float f) {
    uintT u = __builtin_bit_cast(uintT, f);
    u = (u + 0x7fffu + ((u >> 16) & 1u)) >> 16;
    return (ushortT)u;
}

// x,y f32 [b][d][t] -> bf16 [b][t][d]
__global__ __launch_bounds__(1024) void transpose_xy_kernel(const float* __restrict__ x,
                                                            const float* __restrict__ y,
                                                            ushortT* __restrict__ xt,
                                                            ushortT* __restrict__ yt) {
    __shared__ float tile[32][33];
    const int z = blockIdx.z;
    const int bb = z & 7;
    const float* src = (z < 8) ? x : y;
    ushortT* dst = (z < 8) ? xt : yt;
    const int d0 = blockIdx.y * 32;
    const int t0 = blockIdx.x * 32;
    const int tx = threadIdx.x, ty = threadIdx.y;
    tile[ty][tx] = src[((size_t)(bb * DIM + d0 + ty)) * TSZ + t0 + tx];
    __syncthreads();
    dst[((size_t)(bb * TSZ + t0 + ty)) * DIM + d0 + tx] = f2bf(tile[tx][ty]);
}

// W f32 [d][c][i] -> bf16 Wco [i][c][d]
__global__ __launch_bounds__(256) void transpose_w_kernel(const float* __restrict__ W,
                                                          ushortT* __restrict__ Wco) {
    __shared__ float buf[DIM * STEPS];  // 24 KB
    const int d = blockIdx.x;
    for (int idx = threadIdx.x; idx < DIM * STEPS; idx += 256)
        buf[idx] = W[(size_t)d * DIM * STEPS + idx];
    __syncthreads();
    for (int idx = threadIdx.x; idx < DIM * STEPS; idx += 256) {
        const int i = idx >> 9;
        const int c = idx & 511;
        Wco[((size_t)i * DIM + c) * DIM + d] = f2bf(buf[c * STEPS + i]);
    }
}

// ============================ Path A: K1 GEMM ============================
// R15 body unchanged (best measured: 177 us). 128t block, 16 waves x unique
// 32c (W_t=1), XCD-grouping id swizzle, 2 kh staging phases.
__global__ __launch_bounds__(1024, 4) void gemm_kernel(const ushortT* __restrict__ xt,
                                                       const ushortT* __restrict__ Wco,
                                                       const float* __restrict__ bias,
                                                       ushortT* __restrict__ xp) {
    __shared__ ushortT xs[GTCH * 256];  // 64 KB; rows 512 B, 16B-chunk XOR swizzle
    const int id = blockIdx.x;
    const int low = id & 7;
    const int m = id >> 3;
    const int i = m % 12;
    const int gh = m / 12;              // 0..15
    const int g2 = gh * 8 + low;        // group 0..127
    const int tchunk = g2 & 15;
    const int bb = g2 >> 4;
    const int t0 = tchunk * GTCH;
    const int tid = threadIdx.x;
    const int lane = tid & 63;
    const int w = tid >> 6;             // wave 0..15, owns c-range w*32
    const int r16 = lane & 15;
    const int g = lane >> 4;

    const ushortT* gbase = xt + ((size_t)bb * TSZ + t0) * DIM;
    const ushortT* wbase = Wco + (size_t)i * DIM * DIM + (size_t)(w * 32 + r16) * DIM + 8 * g;
    f32x4 acc[8][2] = {};   // [t-tile][c-tile]

    #pragma unroll
    for (int kh = 0; kh < 2; ++kh) {
        // ---- stage x[t0..t0+127][kh*256 .. +256] (64 KB), swizzled ----
        #pragma unroll
        for (int p = 0; p < 4; ++p) {
            const int chunk = p * 1024 + tid;   // 0..4095 (16B chunks)
            const int row = chunk >> 5;         // t row 0..127 (32 chunks/row)
            const int cl = chunk & 31;
            const int csrc = cl ^ (row & 7);
            __builtin_amdgcn_global_load_lds(
                (const AS1 uintT*)(gbase + (size_t)row * DIM + kh * 256 + csrc * 8),
                (AS3 uintT*)(&xs[chunk * 8]), 16, 0, 0);
        }
        __syncthreads();

        #pragma unroll
        for (int kt8 = 0; kt8 < 8; ++kt8) {
            const int kt = kh * 8 + kt8;
            short8v af[2];
            #pragma unroll
            for (int cc = 0; cc < 2; ++cc)
                af[cc] = *(const short8v*)(wbase + (size_t)cc * 16 * DIM + kt * 32);
            #pragma unroll
            for (int t4 = 0; t4 < 8; ++t4) {
                const int row = t4 * 16 + r16;
                const int cidx = (kt8 * 4 + g) ^ (row & 7);
                const short8v bfr = *(const short8v*)(&xs[row * 256 + cidx * 8]);
                acc[t4][0] = __builtin_amdgcn_mfma_f32_16x16x32_bf16(af[0], bfr, acc[t4][0], 0, 0, 0);
                acc[t4][1] = __builtin_amdgcn_mfma_f32_16x16x32_bf16(af[1], bfr, acc[t4][1], 0, 0, 0);
            }
        }
        __syncthreads();   // all reads done before next kh's staging
    }

    // epilogue: + bias, bf16, direct stores
    ushortT* xrow = xp + (((size_t)bb * STEPS + i) * TSZ + t0) * DIM;
    #pragma unroll
    for (int cc = 0; cc < 2; ++cc) {
        const int c0 = w * 32 + cc * 16 + 4 * g;
        const float4 bv = *(const float4*)(bias + c0);
        #pragma unroll
        for (int t4 = 0; t4 < 8; ++t4) {
            const f32x4 v = acc[t4][cc];
            ushort4 h;
            h.x = f2bf(v[0] + bv.x);
            h.y = f2bf(v[1] + bv.y);
            h.z = f2bf(v[2] + bv.z);
            h.w = f2bf(v[3] + bv.w);
            *(ushort4*)(xrow + (size_t)(t4 * 16 + r16) * DIM + c0) = h;
        }
    }
}

// ============================ Path A: K2 predictions ============================
// Block = (bb, tau-tile of 16). Wave w (0..10) owns negative-index n=w; keeps
// its 16 target-row fragments in registers for all 12 steps. Staging batched
// into TWO big bursts (8 sub-tiles = 128 KB, then 4 more overlapped with
// compute): the old 6 stage->drain rounds each paid a full vmcnt(0) drain
// with only ~850cy of compute cover; big bursts run at memory BW.
#define STAGE_SUB(sbuf, ii)                                                          \
    {                                                                                \
        const int offp = (ii) + 1;                                                   \
        const ushortT* srcp = xpb + (size_t)(ii) * TSZ * DIM;                        \
        for (int c = tid; c < 1024; c += 768) {                                      \
            const int row = c >> 6;                                                  \
            const int cl = c & 63;                                                   \
            const int csrc = cl ^ (row & 7);                                         \
            const int rt = max(tau0 - offp + row, 0);                                \
            __builtin_amdgcn_global_load_lds(                                        \
                (const AS1 uintT*)(srcp + (size_t)rt * DIM + csrc * 8),              \
                (AS3 uintT*)(&as[sbuf][c * 8]), 16, 0, 0);                           \
        }                                                                            \
    }

#define COMPUTE_SUB(sbuf, ii)                                                        \
    if (active) {                                                                    \
        f32x4 pacc = {};                                                             \
        _Pragma("unroll")                                                            \
        for (int kt = 0; kt < 16; ++kt) {                                            \
            const short8v af = *(const short8v*)(&as[sbuf][r16 * DIM + (((kt * 4 + g) ^ (r16 & 7)) << 3)]); \
            pacc = __builtin_amdgcn_mfma_f32_16x16x32_bf16(af, bf[kt], pacc, 0, 0, 0); \
        }                                                                            \
        const int t = tau - ((ii) + 1);                                              \
        if (isdiag && t >= 0) {                                                      \
            const size_t segoff = 88ull * (2047ull * (size_t)(ii) - (size_t)((ii) * ((ii) - 1)) / 2); \
            const float v01 = (treg & 1) ? pacc[1] : pacc[0];                        \
            const float v23 = (treg & 1) ? pacc[3] : pacc[2];                        \
            const float v = (treg & 2) ? v23 : v01;                                  \
            out[segoff + ((size_t)t * BSZ + bb) * COPIES + n] = v;                   \
        }                                                                            \
    }

__global__ __launch_bounds__(768, 2) void predict_kernel(const ushortT* __restrict__ xp,
                                                         const ushortT* __restrict__ yt,
                                                         const int* __restrict__ neg,
                                                         float* __restrict__ out) {
    __shared__ ushortT as[8][16 * DIM];  // 8 x 16 KB = 128 KB
    const int id = blockIdx.x;
    const int bb = id & 7;
    const int tau0 = (id >> 3) * 16;
    const int tid = threadIdx.x;
    const int lane = tid & 63;
    const int w = tid >> 6;        // 0..11; waves 0..10 active (n = w)
    const int r16 = lane & 15;
    const int g = lane >> 4;
    const int n = w;
    const int tau = tau0 + r16;
    const bool active = (n < COPIES);
    const bool isdiag = (g == (r16 >> 2));
    const int treg = r16 & 3;

    // persistent B fragments: this lane's full 1 KB target row, 16 x 16 B
    short8v bf[16];
    if (active) {
        const int col = (n == 0) ? (bb * TSZ + tau)
                                 : neg[bb * (NNEG * TSZ) + (n - 1) * TSZ + tau];
        const ushortT* bp = yt + (size_t)col * DIM + g * 8;
        #pragma unroll
        for (int kt = 0; kt < 16; ++kt) bf[kt] = *(const short8v*)(bp + kt * 32);
    }

    const ushortT* xpb = xp + ((size_t)bb * STEPS) * (size_t)TSZ * DIM;

    // phase 1: burst-stage steps 0..7 (128 KB), one drain
    #pragma unroll
    for (int s = 0; s < 8; ++s) STAGE_SUB(s, s)
    __syncthreads();

    // compute steps 0..3
    #pragma unroll
    for (int s = 0; s < 4; ++s) COMPUTE_SUB(s, s)
    __syncthreads();   // bufs 0..3 free

    // phase 2: stage steps 8..11 into bufs 0..3, overlapped with compute 4..7
    #pragma unroll
    for (int s = 0; s < 4; ++s) STAGE_SUB(s, s + 8)
    #pragma unroll
    for (int s = 4; s < 8; ++s) COMPUTE_SUB(s, s)
    __syncthreads();   // drains stage 8..11 (partially covered by compute 4..7)

    // compute steps 8..11
    #pragma unroll
    for (int s = 0; s < 4; ++s) COMPUTE_SUB(s, s + 8)
}

// ============================ Path B fallback (R4 fused) ============================
__global__ __launch_bounds__(512, 4) void fused_kernel(const ushortT* __restrict__ xt,
                                                       const ushortT* __restrict__ yt,
                                                       const ushortT* __restrict__ Wco,
                                                       const float* __restrict__ bias,
                                                       const int* __restrict__ neg,
                                                       float* __restrict__ out) {
    __shared__ ushortT xs[TCH * DIM];
    const int id = blockIdx.x;
    const int bb = id & 7;
    const int id2 = id >> 3;
    const int i = id2 % 12;
    const int tchunk = id2 / 12;
    const int t0 = tchunk * TCH;
    const int tid = threadIdx.x;
    const int lane = tid & 63;
    const int w = tid >> 6;
    const int r16 = lane & 15;
    const int g = lane >> 4;

    {
        const ushortT* gbase = xt + ((size_t)bb * TSZ + t0) * DIM;
        #pragma unroll
        for (int p = 0; p < 8; ++p) {
            const int chunk = p * 512 + tid;
            const int row = chunk >> 6;
            const int cl = chunk & 63;
            const int csrc = cl ^ (row & 7);
            __builtin_amdgcn_global_load_lds(
                (const AS1 uintT*)(gbase + (size_t)row * DIM + csrc * 8),
                (AS3 uintT*)(&xs[chunk * 8]), 16, 0, 0);
        }
    }
    __syncthreads();

    f32x4 acc[4][4] = {};
    const ushortT* wbase = Wco + (size_t)i * DIM * DIM + (size_t)(w * 64 + r16) * DIM + 8 * g;
    #pragma unroll 2
    for (int kt = 0; kt < 16; ++kt) {
        short8v bfr[4];
        #pragma unroll
        for (int t4 = 0; t4 < 4; ++t4) {
            const int row = t4 * 16 + r16;
            bfr[t4] = *(const short8v*)(&xs[row * DIM + (((kt * 4 + g) ^ (row & 7)) << 3)]);
        }
        #pragma unroll
        for (int cc = 0; cc < 4; ++cc) {
            const short8v af = *(const short8v*)(wbase + (size_t)cc * 16 * DIM + kt * 32);
            #pragma unroll
            for (int t4 = 0; t4 < 4; ++t4)
                acc[t4][cc] = __builtin_amdgcn_mfma_f32_16x16x32_bf16(af, bfr[t4], acc[t4][cc], 0, 0, 0);
        }
    }
    __syncthreads();

    #pragma unroll
    for (int cc = 0; cc < 4; ++cc) {
        const int c0 = w * 64 + cc * 16 + 4 * g;
        const float4 bv = *(const float4*)(bias + c0);
        #pragma unroll
        for (int t4 = 0; t4 < 4; ++t4) {
            const f32x4 v = acc[t4][cc];
            ushort4 h;
            h.x = f2bf(v[0] + bv.x);
            h.y = f2bf(v[1] + bv.y);
            h.z = f2bf(v[2] + bv.z);
            h.w = f2bf(v[3] + bv.w);
            const int tloc = t4 * 16 + r16;
            const int pchunk = ((c0 >> 3) ^ (tloc & 7));
            *(ushort4*)(&xs[tloc * DIM + (pchunk << 3) + (g & 1) * 4]) = h;
        }
    }
    __syncthreads();

    const int off = i + 1;
    const int tlim = TSZ - off;
    const size_t segoff = 88ull * (2047ull * (size_t)i - (size_t)(i * (i - 1)) / 2);
    const int tt = w & 3;
    const int t00 = tt * 16;
    const int nbase = (w >> 2) * 5;
    const int arow = t00 + r16;
    const int tb = t0 + t00 + r16;
    const int tauc = min(tb + off, TSZ - 1);
    const bool isdiag = (g == (r16 >> 2));
    const int treg = r16 & 3;

    const ushortT* bptrs[6];
    #pragma unroll
    for (int nj = 0; nj < 6; ++nj) {
        const int nn = nbase + nj;
        const int col = (nn == 0) ? (bb * TSZ + tauc)
                                  : neg[bb * (NNEG * TSZ) + (nn - 1) * TSZ + tauc];
        bptrs[nj] = yt + (size_t)col * DIM + g * 8;
    }

    f32x4 pacc[6] = {};
    #pragma unroll
    for (int kt = 0; kt < 16; ++kt) {
        const short8v af = *(const short8v*)(&xs[arow * DIM + (((kt * 4 + g) ^ (arow & 7)) << 3)]);
        #pragma unroll
        for (int nj = 0; nj < 6; ++nj) {
            const short8v bfv = *(const short8v*)(bptrs[nj] + kt * 32);
            pacc[nj] = __builtin_amdgcn_mfma_f32_16x16x32_bf16(af, bfv, pacc[nj], 0, 0, 0);
        }
    }

    if (isdiag && tb < tlim) {
        #pragma unroll
        for (int nj = 0; nj < 6; ++nj) {
            const float v01 = (treg & 1) ? pacc[nj][1] : pacc[nj][0];
            const float v23 = (treg & 1) ? pacc[nj][3] : pacc[nj][2];
            const float v = (treg & 2) ? v23 : v01;
            out[segoff + ((size_t)tb * BSZ + bb) * COPIES + (nbase + nj)] = v;
        }
    }
}

__global__ __launch_bounds__(256) void labels_kernel(float* __restrict__ out) {
    const int idx = blockIdx.x * 256 + threadIdx.x;
    if (idx < 195984) out[2155824 + idx] = 0.0f;
}

extern "C" void kernel_launch(void* const* d_in, const int* in_sizes, int n_in,
                              void* d_out, int out_size, void* d_ws, size_t ws_size,
                              hipStream_t stream) {
    const float* x = (const float*)d_in[0];
    const float* y = (const float*)d_in[1];
    const float* W = (const float*)d_in[2];
    const float* b = (const float*)d_in[3];
    const int* neg = (const int*)d_in[4];
    float* out = (float*)d_out;
    ushortT* xt = (ushortT*)d_ws;
    ushortT* yt = (ushortT*)((char*)d_ws + 16777216);
    ushortT* Wco = (ushortT*)((char*)d_ws + 33554432);

    transpose_xy_kernel<<<dim3(TSZ / 32, DIM / 32, 16), dim3(32, 32), 0, stream>>>(x, y, xt, yt);
    transpose_w_kernel<<<dim3(DIM), dim3(256), 0, stream>>>(W, Wco);

    if (ws_size >= WS_NEEDED) {
        ushortT* xp = (ushortT*)((char*)d_ws + XP_OFF);
        gemm_kernel<<<dim3(BSZ * STEPS * (TSZ / GTCH)), dim3(1024), 0, stream>>>(xt, Wco, b, xp);
        predict_kernel<<<dim3(BSZ * (TSZ / 16)), dim3(768), 0, stream>>>(xp, yt, neg, out);
    } else {
        fused_kernel<<<dim3(BSZ * STEPS * (TSZ / TCH)), dim3(512), 0, stream>>>(xt, yt, Wco, b, neg, out);
    }
    labels_kernel<<<dim3(766), dim3(256), 0, stream>>>(out);
}

// Round 17
// 283.047 us; speedup vs baseline: 1.0255x; 1.0255x over previous
//
#include <hip/hip_runtime.h>

#define BSZ 8
#define DIM 512
#define TSZ 2048
#define STEPS 12
#define NNEG 10
#define COPIES 11
#define TCH 64
#define GTCH 128

typedef unsigned short ushortT;
typedef unsigned int uintT;
typedef __attribute__((ext_vector_type(8))) short short8v;
typedef __attribute__((ext_vector_type(4))) float f32x4;

#define AS1 __attribute__((address_space(1)))
#define AS3 __attribute__((address_space(3)))

// ws layout (bytes):
//   xt : [8][2048][512] bf16 @ 0            (16,777,216)
//   yt : [8][2048][512] bf16 @ 16,777,216   (16,777,216)
//   Wco: [12][512][512] bf16 @ 33,554,432   (6,291,456)
//   xp : [8][12][2048][512] bf16 @ 39,845,888 (201,326,592)  -- Path A only
#define XP_OFF 39845888ull
#define WS_NEEDED (XP_OFF + 201326592ull)

__device__ __forceinline__ ushortT f2bf(float f) {
    uintT u = __builtin_bit_cast(uintT, f);
    u = (u + 0x7fffu + ((u >> 16) & 1u)) >> 16;
    return (ushortT)u;
}

// x,y f32 [b][d][t] -> bf16 [b][t][d]
__global__ __launch_bounds__(1024) void transpose_xy_kernel(const float* __restrict__ x,
                                                            const float* __restrict__ y,
                                                            ushortT* __restrict__ xt,
                                                            ushortT* __restrict__ yt) {
    __shared__ float tile[32][33];
    const int z = blockIdx.z;
    const int bb = z & 7;
    const float* src = (z < 8) ? x : y;
    ushortT* dst = (z < 8) ? xt : yt;
    const int d0 = blockIdx.y * 32;
    const int t0 = blockIdx.x * 32;
    const int tx = threadIdx.x, ty = threadIdx.y;
    tile[ty][tx] = src[((size_t)(bb * DIM + d0 + ty)) * TSZ + t0 + tx];
    __syncthreads();
    dst[((size_t)(bb * TSZ + t0 + ty)) * DIM + d0 + tx] = f2bf(tile[tx][ty]);
}

// W f32 [d][c][i] -> bf16 Wco [i][c][d]
__global__ __launch_bounds__(256) void transpose_w_kernel(const float* __restrict__ W,
                                                          ushortT* __restrict__ Wco) {
    __shared__ float buf[DIM * STEPS];  // 24 KB
    const int d = blockIdx.x;
    for (int idx = threadIdx.x; idx < DIM * STEPS; idx += 256)
        buf[idx] = W[(size_t)d * DIM * STEPS + idx];
    __syncthreads();
    for (int idx = threadIdx.x; idx < DIM * STEPS; idx += 256) {
        const int i = idx >> 9;
        const int c = idx & 511;
        Wco[((size_t)i * DIM + c) * DIM + d] = f2bf(buf[c * STEPS + i]);
    }
}

// ============================ Path A: K1 GEMM ============================
// R15 geometry (128t block, 16 waves x unique 32c, W_t=1, XCD-grouping id
// swizzle) with SINGLE full-K staging: 128 KB x-tile staged in one burst,
// ONE drain+barrier, then an uninterrupted fully-unrolled 16-kt MFMA region
// (no mid-kernel barriers). At 1 block/CU the old 2-phase structure exposed
// two full stage drains and split the compute pipeline; this removes both.
__global__ __launch_bounds__(1024, 4) void gemm_kernel(const ushortT* __restrict__ xt,
                                                       const ushortT* __restrict__ Wco,
                                                       const float* __restrict__ bias,
                                                       ushortT* __restrict__ xp) {
    __shared__ ushortT xs[GTCH * DIM];  // 128 KB; rows 1 KB, 16B-chunk XOR swizzle
    const int id = blockIdx.x;
    const int low = id & 7;
    const int m = id >> 3;
    const int i = m % 12;
    const int gh = m / 12;              // 0..15
    const int g2 = gh * 8 + low;        // group 0..127
    const int tchunk = g2 & 15;
    const int bb = g2 >> 4;
    const int t0 = tchunk * GTCH;
    const int tid = threadIdx.x;
    const int lane = tid & 63;
    const int w = tid >> 6;             // wave 0..15, owns c-range w*32
    const int r16 = lane & 15;
    const int g = lane >> 4;

    const ushortT* gbase = xt + ((size_t)bb * TSZ + t0) * DIM;
    const ushortT* wbase = Wco + (size_t)i * DIM * DIM + (size_t)(w * 32 + r16) * DIM + 8 * g;
    f32x4 acc[8][2] = {};   // [t-tile][c-tile]

    // ---- stage the full x[t0..t0+127][0..512] tile (128 KB), one burst ----
    #pragma unroll
    for (int p = 0; p < 8; ++p) {
        const int chunk = p * 1024 + tid;   // 0..8191 (16B chunks)
        const int row = chunk >> 6;         // t row 0..127 (64 chunks/row)
        const int cl = chunk & 63;
        const int csrc = cl ^ (row & 7);
        __builtin_amdgcn_global_load_lds(
            (const AS1 uintT*)(gbase + (size_t)row * DIM + csrc * 8),
            (AS3 uintT*)(&xs[chunk * 8]), 16, 0, 0);
    }
    __syncthreads();   // the ONLY barrier

    // ---- full-K compute: 16 kt, no barriers ----
    #pragma unroll
    for (int kt = 0; kt < 16; ++kt) {
        short8v af[2];
        #pragma unroll
        for (int cc = 0; cc < 2; ++cc)
            af[cc] = *(const short8v*)(wbase + (size_t)cc * 16 * DIM + kt * 32);
        #pragma unroll
        for (int t4 = 0; t4 < 8; ++t4) {
            const int row = t4 * 16 + r16;
            const int cidx = (kt * 4 + g) ^ (row & 7);
            const short8v bfr = *(const short8v*)(&xs[row * DIM + cidx * 8]);
            acc[t4][0] = __builtin_amdgcn_mfma_f32_16x16x32_bf16(af[0], bfr, acc[t4][0], 0, 0, 0);
            acc[t4][1] = __builtin_amdgcn_mfma_f32_16x16x32_bf16(af[1], bfr, acc[t4][1], 0, 0, 0);
        }
    }

    // epilogue: + bias, bf16, direct stores
    ushortT* xrow = xp + (((size_t)bb * STEPS + i) * TSZ + t0) * DIM;
    #pragma unroll
    for (int cc = 0; cc < 2; ++cc) {
        const int c0 = w * 32 + cc * 16 + 4 * g;
        const float4 bv = *(const float4*)(bias + c0);
        #pragma unroll
        for (int t4 = 0; t4 < 8; ++t4) {
            const f32x4 v = acc[t4][cc];
            ushort4 h;
            h.x = f2bf(v[0] + bv.x);
            h.y = f2bf(v[1] + bv.y);
            h.z = f2bf(v[2] + bv.z);
            h.w = f2bf(v[3] + bv.w);
            *(ushort4*)(xrow + (size_t)(t4 * 16 + r16) * DIM + c0) = h;
        }
    }
}

// ============================ Path A: K2 predictions ============================
// Block = (bb, tau-tile of 16). Wave w (0..10) owns negative-index n=w; keeps
// its 16 target-row fragments in registers for all 12 steps. Staging batched
// into two big bursts (8 sub-tiles = 128 KB, then 4 more overlapped with
// compute).
#define STAGE_SUB(sbuf, ii)                                                          \
    {                                                                                \
        const int offp = (ii) + 1;                                                   \
        const ushortT* srcp = xpb + (size_t)(ii) * TSZ * DIM;                        \
        for (int c = tid; c < 1024; c += 768) {                                      \
            const int row = c >> 6;                                                  \
            const int cl = c & 63;                                                   \
            const int csrc = cl ^ (row & 7);                                         \
            const int rt = max(tau0 - offp + row, 0);                                \
            __builtin_amdgcn_global_load_lds(                                        \
                (const AS1 uintT*)(srcp + (size_t)rt * DIM + csrc * 8),              \
                (AS3 uintT*)(&as[sbuf][c * 8]), 16, 0, 0);                           \
        }                                                                            \
    }

#define COMPUTE_SUB(sbuf, ii)                                                        \
    if (active) {                                                                    \
        f32x4 pacc = {};                                                             \
        _Pragma("unroll")                                                            \
        for (int kt = 0; kt < 16; ++kt) {                                            \
            const short8v af = *(const short8v*)(&as[sbuf][r16 * DIM + (((kt * 4 + g) ^ (r16 & 7)) << 3)]); \
            pacc = __builtin_amdgcn_mfma_f32_16x16x32_bf16(af, bf[kt], pacc, 0, 0, 0); \
        }                                                                            \
        const int t = tau - ((ii) + 1);                                              \
        if (isdiag && t >= 0) {                                                      \
            const size_t segoff = 88ull * (2047ull * (size_t)(ii) - (size_t)((ii) * ((ii) - 1)) / 2); \
            const float v01 = (treg & 1) ? pacc[1] : pacc[0];                        \
            const float v23 = (treg & 1) ? pacc[3] : pacc[2];                        \
            const float v = (treg & 2) ? v23 : v01;                                  \
            out[segoff + ((size_t)t * BSZ + bb) * COPIES + n] = v;                   \
        }                                                                            \
    }

__global__ __launch_bounds__(768, 2) void predict_kernel(const ushortT* __restrict__ xp,
                                                         const ushortT* __restrict__ yt,
                                                         const int* __restrict__ neg,
                                                         float* __restrict__ out) {
    __shared__ ushortT as[8][16 * DIM];  // 8 x 16 KB = 128 KB
    const int id = blockIdx.x;
    const int bb = id & 7;
    const int tau0 = (id >> 3) * 16;
    const int tid = threadIdx.x;
    const int lane = tid & 63;
    const int w = tid >> 6;        // 0..11; waves 0..10 active (n = w)
    const int r16 = lane & 15;
    const int g = lane >> 4;
    const int n = w;
    const int tau = tau0 + r16;
    const bool active = (n < COPIES);
    const bool isdiag = (g == (r16 >> 2));
    const int treg = r16 & 3;

    // persistent B fragments: this lane's full 1 KB target row, 16 x 16 B
    short8v bf[16];
    if (active) {
        const int col = (n == 0) ? (bb * TSZ + tau)
                                 : neg[bb * (NNEG * TSZ) + (n - 1) * TSZ + tau];
        const ushortT* bp = yt + (size_t)col * DIM + g * 8;
        #pragma unroll
        for (int kt = 0; kt < 16; ++kt) bf[kt] = *(const short8v*)(bp + kt * 32);
    }

    const ushortT* xpb = xp + ((size_t)bb * STEPS) * (size_t)TSZ * DIM;

    // phase 1: burst-stage steps 0..7 (128 KB), one drain
    #pragma unroll
    for (int s = 0; s < 8; ++s) STAGE_SUB(s, s)
    __syncthreads();

    // compute steps 0..3
    #pragma unroll
    for (int s = 0; s < 4; ++s) COMPUTE_SUB(s, s)
    __syncthreads();   // bufs 0..3 free

    // phase 2: stage steps 8..11 into bufs 0..3, overlapped with compute 4..7
    #pragma unroll
    for (int s = 0; s < 4; ++s) STAGE_SUB(s, s + 8)
    #pragma unroll
    for (int s = 4; s < 8; ++s) COMPUTE_SUB(s, s)
    __syncthreads();   // drains stage 8..11 (partially covered by compute 4..7)

    // compute steps 8..11
    #pragma unroll
    for (int s = 0; s < 4; ++s) COMPUTE_SUB(s, s + 8)
}

// ============================ Path B fallback (R4 fused) ============================
__global__ __launch_bounds__(512, 4) void fused_kernel(const ushortT* __restrict__ xt,
                                                       const ushortT* __restrict__ yt,
                                                       const ushortT* __restrict__ Wco,
                                                       const float* __restrict__ bias,
                                                       const int* __restrict__ neg,
                                                       float* __restrict__ out) {
    __shared__ ushortT xs[TCH * DIM];
    const int id = blockIdx.x;
    const int bb = id & 7;
    const int id2 = id >> 3;
    const int i = id2 % 12;
    const int tchunk = id2 / 12;
    const int t0 = tchunk * TCH;
    const int tid = threadIdx.x;
    const int lane = tid & 63;
    const int w = tid >> 6;
    const int r16 = lane & 15;
    const int g = lane >> 4;

    {
        const ushortT* gbase = xt + ((size_t)bb * TSZ + t0) * DIM;
        #pragma unroll
        for (int p = 0; p < 8; ++p) {
            const int chunk = p * 512 + tid;
            const int row = chunk >> 6;
            const int cl = chunk & 63;
            const int csrc = cl ^ (row & 7);
            __builtin_amdgcn_global_load_lds(
                (const AS1 uintT*)(gbase + (size_t)row * DIM + csrc * 8),
                (AS3 uintT*)(&xs[chunk * 8]), 16, 0, 0);
        }
    }
    __syncthreads();

    f32x4 acc[4][4] = {};
    const ushortT* wbase = Wco + (size_t)i * DIM * DIM + (size_t)(w * 64 + r16) * DIM + 8 * g;
    #pragma unroll 2
    for (int kt = 0; kt < 16; ++kt) {
        short8v bfr[4];
        #pragma unroll
        for (int t4 = 0; t4 < 4; ++t4) {
            const int row = t4 * 16 + r16;
            bfr[t4] = *(const short8v*)(&xs[row * DIM + (((kt * 4 + g) ^ (row & 7)) << 3)]);
        }
        #pragma unroll
        for (int cc = 0; cc < 4; ++cc) {
            const short8v af = *(const short8v*)(wbase + (size_t)cc * 16 * DIM + kt * 32);
            #pragma unroll
            for (int t4 = 0; t4 < 4; ++t4)
                acc[t4][cc] = __builtin_amdgcn_mfma_f32_16x16x32_bf16(af, bfr[t4], acc[t4][cc], 0, 0, 0);
        }
    }
    __syncthreads();

    #pragma unroll
    for (int cc = 0; cc < 4; ++cc) {
        const int c0 = w * 64 + cc * 16 + 4 * g;
        const float4 bv = *(const float4*)(bias + c0);
        #pragma unroll
        for (int t4 = 0; t4 < 4; ++t4) {
            const f32x4 v = acc[t4][cc];
            ushort4 h;
            h.x = f2bf(v[0] + bv.x);
            h.y = f2bf(v[1] + bv.y);
            h.z = f2bf(v[2] + bv.z);
            h.w = f2bf(v[3] + bv.w);
            const int tloc = t4 * 16 + r16;
            const int pchunk = ((c0 >> 3) ^ (tloc & 7));
            *(ushort4*)(&xs[tloc * DIM + (pchunk << 3) + (g & 1) * 4]) = h;
        }
    }
    __syncthreads();

    const int off = i + 1;
    const int tlim = TSZ - off;
    const size_t segoff = 88ull * (2047ull * (size_t)i - (size_t)(i * (i - 1)) / 2);
    const int tt = w & 3;
    const int t00 = tt * 16;
    const int nbase = (w >> 2) * 5;
    const int arow = t00 + r16;
    const int tb = t0 + t00 + r16;
    const int tauc = min(tb + off, TSZ - 1);
    const bool isdiag = (g == (r16 >> 2));
    const int treg = r16 & 3;

    const ushortT* bptrs[6];
    #pragma unroll
    for (int nj = 0; nj < 6; ++nj) {
        const int nn = nbase + nj;
        const int col = (nn == 0) ? (bb * TSZ + tauc)
                                  : neg[bb * (NNEG * TSZ) + (nn - 1) * TSZ + tauc];
        bptrs[nj] = yt + (size_t)col * DIM + g * 8;
    }

    f32x4 pacc[6] = {};
    #pragma unroll
    for (int kt = 0; kt < 16; ++kt) {
        const short8v af = *(const short8v*)(&xs[arow * DIM + (((kt * 4 + g) ^ (arow & 7)) << 3)]);
        #pragma unroll
        for (int nj = 0; nj < 6; ++nj) {
            const short8v bfv = *(const short8v*)(bptrs[nj] + kt * 32);
            pacc[nj] = __builtin_amdgcn_mfma_f32_16x16x32_bf16(af, bfv, pacc[nj], 0, 0, 0);
        }
    }

    if (isdiag && tb < tlim) {
        #pragma unroll
        for (int nj = 0; nj < 6; ++nj) {
            const float v01 = (treg & 1) ? pacc[nj][1] : pacc[nj][0];
            const float v23 = (treg & 1) ? pacc[nj][3] : pacc[nj][2];
            const float v = (treg & 2) ? v23 : v01;
            out[segoff + ((size_t)tb * BSZ + bb) * COPIES + (nbase + nj)] = v;
        }
    }
}

__global__ __launch_bounds__(256) void labels_kernel(float* __restrict__ out) {
    const int idx = blockIdx.x * 256 + threadIdx.x;
    if (idx < 195984) out[2155824 + idx] = 0.0f;
}

extern "C" void kernel_launch(void* const* d_in, const int* in_sizes, int n_in,
                              void* d_out, int out_size, void* d_ws, size_t ws_size,
                              hipStream_t stream) {
    const float* x = (const float*)d_in[0];
    const float* y = (const float*)d_in[1];
    const float* W = (const float*)d_in[2];
    const float* b = (const float*)d_in[3];
    const int* neg = (const int*)d_in[4];
    float* out = (float*)d_out;
    ushortT* xt = (ushortT*)d_ws;
    ushortT* yt = (ushortT*)((char*)d_ws + 16777216);
    ushortT* Wco = (ushortT*)((char*)d_ws + 33554432);

    transpose_xy_kernel<<<dim3(TSZ / 32, DIM / 32, 16), dim3(32, 32), 0, stream>>>(x, y, xt, yt);
    transpose_w_kernel<<<dim3(DIM), dim3(256), 0, stream>>>(W, Wco);

    if (ws_size >= WS_NEEDED) {
        ushortT* xp = (ushortT*)((char*)d_ws + XP_OFF);
        gemm_kernel<<<dim3(BSZ * STEPS * (TSZ / GTCH)), dim3(1024), 0, stream>>>(xt, Wco, b, xp);
        predict_kernel<<<dim3(BSZ * (TSZ / 16)), dim3(768), 0, stream>>>(xp, yt, neg, out);
    } else {
        fused_kernel<<<dim3(BSZ * STEPS * (TSZ / TCH)), dim3(512), 0, stream>>>(xt, yt, Wco, b, neg, out);
    }
    labels_kernel<<<dim3(766), dim3(256), 0, stream>>>(out);
}